// Round 1
// baseline (616.408 us; speedup 1.0000x reference)
//
#include <hip/hip_runtime.h>
#include <stdint.h>
#include <stddef.h>

#define FEAT 128

// ---------------- graph build ----------------

__global__ __launch_bounds__(256) void k_zero(int* __restrict__ deg, int* __restrict__ allocCtr, int n) {
  int i = blockIdx.x * 256 + threadIdx.x;
  if (i < n) deg[i] = 0;
  if (i == 0 && blockIdx.x == 0) allocCtr[0] = 0;
}

__global__ __launch_bounds__(256) void k_deg(const int* __restrict__ dst, int* __restrict__ deg, int E) {
  int e = blockIdx.x * 256 + threadIdx.x;
  if (e < E) atomicAdd(&deg[dst[e]], 1);
}

// rowstart via atomic bump allocation: inter-node row order is irrelevant for the
// aggregation (each node only reads its own row range), so no prefix scan needed.
__global__ __launch_bounds__(256) void k_nodeinit(const int* __restrict__ deg, int* __restrict__ rowstart,
                                                  int* __restrict__ cursor, float* __restrict__ dis,
                                                  int* __restrict__ allocCtr, int n) {
  int i = blockIdx.x * 256 + threadIdx.x;
  if (i >= n) return;
  int d = deg[i];
  int s = atomicAdd(allocCtr, d);
  rowstart[i] = s;
  cursor[i] = s;
  dis[i] = rsqrtf((float)(d + 1));  // +1: self-loop included in reference degree
}

__global__ __launch_bounds__(256) void k_scatter(const int* __restrict__ src, const int* __restrict__ dst,
                                                 int* __restrict__ cursor, int* __restrict__ adj, int E) {
  int e = blockIdx.x * 256 + threadIdx.x;
  if (e >= E) return;
  int pos = atomicAdd(&cursor[dst[e]], 1);
  adj[pos] = src[e];
}

// ---------------- aggregation: z[i] = dis[i] * ( dis[i]*h[i] + sum_j dis[j]*h[j] ) ----------------
// one wave per node; lane l owns features l and l+64 (two coalesced 256B gathers per neighbor)

__global__ __launch_bounds__(256) void k_agg(const float* __restrict__ h, float* __restrict__ z,
                                             const int* __restrict__ adj, const int* __restrict__ rowstart,
                                             const int* __restrict__ deg, const float* __restrict__ dis, int n) {
  int node = blockIdx.x * 4 + (threadIdx.x >> 6);
  if (node >= n) return;
  int lane = threadIdx.x & 63;
  int rs = rowstart[node];
  int d = deg[node];
  float di = dis[node];
  const float* hrow = h + (size_t)node * FEAT;
  float a0 = di * hrow[lane];
  float a1 = di * hrow[lane + 64];
  int e = rs + d;
#pragma unroll 4
  for (int p = rs; p < e; ++p) {
    int j = adj[p];
    float dj = dis[j];
    const float* hj = h + (size_t)j * FEAT;
    a0 = fmaf(dj, hj[lane], a0);
    a1 = fmaf(dj, hj[lane + 64], a1);
  }
  z[(size_t)node * FEAT + lane] = di * a0;
  z[(size_t)node * FEAT + lane + 64] = di * a1;
}

// ---------------- fused GEMM + bias + relu: Out = relu(Z @ W + b) ----------------
// W entirely in LDS as float2-interleaved [k][c] = {W[k][c], W[k][c+64]}.
// 64 rows per block, 4 rows per wave-group, lane computes cols (l, l+64) for 4 rows.

__global__ __launch_bounds__(256) void k_gemm(const float* __restrict__ Z, const float* __restrict__ W,
                                              const float* __restrict__ bias, float* __restrict__ Out, int n) {
  __shared__ float2 Wl[128][64];              // 64 KB
  __shared__ float2 bl[64];                   // 512 B
  __shared__ __align__(16) float zrow[4][4][128];  // 8 KB (per-wave private)
  const int tid = threadIdx.x;

  for (int idx = tid; idx < 128 * 64; idx += 256) {
    int k = idx >> 6, c = idx & 63;
    Wl[k][c] = make_float2(W[k * 128 + c], W[k * 128 + c + 64]);
  }
  if (tid < 64) bl[tid] = make_float2(bias[tid], bias[tid + 64]);
  __syncthreads();

  const int wave = tid >> 6, lane = tid & 63;
  const int base = blockIdx.x * 64;

  for (int g = 0; g < 4; ++g) {
    int r0 = base + wave * 4 + g * 16;
    // stage 4 rows of Z into per-wave LDS (coalesced float2 loads)
#pragma unroll
    for (int r = 0; r < 4; ++r) {
      int rr = r0 + r;
      if (rr < n) ((float2*)zrow[wave][r])[lane] = ((const float2*)(Z + (size_t)rr * FEAT))[lane];
    }
    float2 a0 = {0.f, 0.f}, a1 = {0.f, 0.f}, a2 = {0.f, 0.f}, a3 = {0.f, 0.f};
#pragma unroll 8
    for (int k = 0; k < 128; ++k) {
      float2 w = Wl[k][lane];
      float z0 = zrow[wave][0][k];
      float z1 = zrow[wave][1][k];
      float z2 = zrow[wave][2][k];
      float z3 = zrow[wave][3][k];
      a0.x = fmaf(z0, w.x, a0.x); a0.y = fmaf(z0, w.y, a0.y);
      a1.x = fmaf(z1, w.x, a1.x); a1.y = fmaf(z1, w.y, a1.y);
      a2.x = fmaf(z2, w.x, a2.x); a2.y = fmaf(z2, w.y, a2.y);
      a3.x = fmaf(z3, w.x, a3.x); a3.y = fmaf(z3, w.y, a3.y);
    }
    float2 bb = bl[lane];
    float2 av[4] = {a0, a1, a2, a3};
#pragma unroll
    for (int r = 0; r < 4; ++r) {
      int rr = r0 + r;
      if (rr < n) {
        float vx = fmaxf(av[r].x + bb.x, 0.f);
        float vy = fmaxf(av[r].y + bb.y, 0.f);
        Out[(size_t)rr * FEAT + lane] = vx;
        Out[(size_t)rr * FEAT + lane + 64] = vy;
      }
    }
  }
}

// ---------------- launch ----------------

extern "C" void kernel_launch(void* const* d_in, const int* in_sizes, int n_in,
                              void* d_out, int out_size, void* d_ws, size_t ws_size,
                              hipStream_t stream) {
  const float* x  = (const float*)d_in[0];
  const int*   ei = (const int*)d_in[1];
  const float* W1 = (const float*)d_in[2];
  const float* b1 = (const float*)d_in[3];
  const float* W2 = (const float*)d_in[4];
  const float* b2 = (const float*)d_in[5];
  float* out = (float*)d_out;

  const int n = in_sizes[0] / FEAT;   // 100000
  const int E = in_sizes[1] / 2;      // 1600000
  const int* srcv = ei;
  const int* dstv = ei + E;

  uintptr_t p = (uintptr_t)d_ws;
  auto balloc = [&](size_t bytes) -> void* {
    void* r = (void*)p;
    p += (bytes + 255) & ~(size_t)255;
    return r;
  };
  float* A        = (float*)balloc((size_t)n * FEAT * sizeof(float));  // 51.2 MB
  float* B        = (float*)balloc((size_t)n * FEAT * sizeof(float));  // 51.2 MB
  int*   deg      = (int*)  balloc((size_t)n * sizeof(int));
  int*   rowstart = (int*)  balloc((size_t)n * sizeof(int));
  int*   cursor   = (int*)  balloc((size_t)n * sizeof(int));
  float* dis      = (float*)balloc((size_t)n * sizeof(float));
  int*   allocCtr = (int*)  balloc(256);
  int*   adj      = (int*)  balloc((size_t)E * sizeof(int));           // 6.4 MB
  (void)ws_size; (void)n_in; (void)out_size;

  const int eb = (E + 255) / 256;
  const int nb = (n + 255) / 256;

  // graph build (shared by both layers)
  k_zero    <<<nb, 256, 0, stream>>>(deg, allocCtr, n);
  k_deg     <<<eb, 256, 0, stream>>>(dstv, deg, E);
  k_nodeinit<<<nb, 256, 0, stream>>>(deg, rowstart, cursor, dis, allocCtr, n);
  k_scatter <<<eb, 256, 0, stream>>>(srcv, dstv, cursor, adj, E);

  const int ab = (n + 3) / 4;        // agg: 4 nodes (waves) per block
  const int gb = (n + 63) / 64;      // gemm: 64 rows per block

  // layer 1: h1 = relu((Â x) W1 + b1)
  k_agg <<<ab, 256, 0, stream>>>(x, A, adj, rowstart, deg, dis, n);
  k_gemm<<<gb, 256, 0, stream>>>(A, W1, b1, B, n);

  // layer 2: out = relu((Â h1) W2 + b2)   (pooling is identity: batch = arange(N))
  k_agg <<<ab, 256, 0, stream>>>(B, A, adj, rowstart, deg, dis, n);
  k_gemm<<<gb, 256, 0, stream>>>(A, W2, b2, out, n);
}